// Round 2
// baseline (479.910 us; speedup 1.0000x reference)
//
#include <hip/hip_runtime.h>
#include <stdint.h>
#include <stddef.h>

#define BATCH 16
#define CH    64
#define IH    128
#define IW    128
#define HW    (IH*IW)

typedef __attribute__((ext_vector_type(8))) short short8;
typedef __attribute__((ext_vector_type(4))) short short4v;
typedef __attribute__((ext_vector_type(4))) float f32x4;
typedef __attribute__((ext_vector_type(2))) float f32x2;

__device__ __forceinline__ float bf2f(short s) {
    union { unsigned int u; float f; } v;
    v.u = ((unsigned int)(unsigned short)s) << 16;
    return v.f;
}
__device__ __forceinline__ short f2bf(float f) {
    union { float f; unsigned int u; } v; v.f = f;
    unsigned int r = v.u + 0x7fffu + ((v.u >> 16) & 1u);
    return (short)(r >> 16);
}

// ---------------------------------------------------------------------------
// K0a: x NCHW fp32 -> NHWC bf16 (per-(b,y) row, LDS transpose)
// ---------------------------------------------------------------------------
__global__ __launch_bounds__(256) void prep_x(const float* __restrict__ x,
                                              short* __restrict__ xbf) {
    __shared__ float tile[CH * 129];
    const int b = blockIdx.x >> 7;
    const int y = blockIdx.x & 127;
    const int t = threadIdx.x;
    const float* src = x + (size_t)b * CH * HW + (size_t)y * IW;
    #pragma unroll
    for (int i = 0; i < 32; ++i) {
        int lin = i * 256 + t;
        int c = lin >> 7, xx = lin & 127;
        tile[c * 129 + xx] = src[(size_t)c * HW + xx];
    }
    __syncthreads();
    unsigned int* dst = (unsigned int*)(xbf + ((size_t)(b * IH + y) * IW) * CH);
    #pragma unroll
    for (int j = 0; j < 16; ++j) {
        int lin = j * 256 + t;
        int c2 = lin & 31, xx = lin >> 5;
        unsigned int lo = (unsigned int)(unsigned short)f2bf(tile[(2 * c2) * 129 + xx]);
        unsigned int hi = (unsigned int)(unsigned short)f2bf(tile[(2 * c2 + 1) * 129 + xx]);
        dst[xx * 32 + c2] = lo | (hi << 16);
    }
}

// ---------------------------------------------------------------------------
// K0b: weights fp32 [b][co][ci][3][3] -> bf16 [b][co][tap][ci]  (both sets)
// ---------------------------------------------------------------------------
#define WTOT 589824  // 16*64*9*64
__global__ __launch_bounds__(256) void prep_w(const float* __restrict__ w1,
                                              const float* __restrict__ w2,
                                              short* __restrict__ w1t,
                                              short* __restrict__ w2t) {
    int o = blockIdx.x * 1024 + threadIdx.x * 4;
    const float* src; short* dst;
    if (o >= WTOT) { src = w2; dst = w2t; o -= WTOT; }
    else           { src = w1; dst = w1t; }
    int cin = o & 63;
    int tap = (o >> 6) % 9;
    int bc  = o / 576;
    #pragma unroll
    for (int k = 0; k < 4; ++k)
        dst[(size_t)bc * 576 + tap * 64 + cin + k] =
            f2bf(src[(size_t)bc * 576 + (cin + k) * 9 + tap]);
}

// ---------------------------------------------------------------------------
// Conv kernel: implicit GEMM, M=64 couts x N=256 px (2 rows), K=576.
// in/out NHWC bf16, wt [b][co][tap][ci] bf16. Fused sum/sumsq stats (atomics).
// ---------------------------------------------------------------------------
#define LCOLS 130
#define CSTR  40                 // shorts per col slot (32 used + 8 pad)
#define RSTR  (LCOLS * CSTR)     // 5200 shorts per row
#define WSTR  296                // shorts per cout (288 used + 8 pad)

__global__ __launch_bounds__(256) void conv_kernel(
    const short* __restrict__ in, const short* __restrict__ wt,
    short* __restrict__ out, float* __restrict__ stats) {

    __shared__ short in_tile[4 * RSTR];   // 41600 B
    __shared__ short w_tile[64 * WSTR];   // 37888 B

    const int b    = blockIdx.y;
    const int y0   = blockIdx.x * 2;
    const int t    = threadIdx.x;
    const int lane = t & 63;
    const int wave = t >> 6;
    const int l15  = lane & 15;
    const int q    = lane >> 4;

    const f32x4 zero4 = {0.f, 0.f, 0.f, 0.f};
    f32x4 acc[4][4];
    #pragma unroll
    for (int mi = 0; mi < 4; ++mi)
        #pragma unroll
        for (int ni = 0; ni < 4; ++ni) acc[mi][ni] = zero4;

    int aBase[4], bBase[4];
    #pragma unroll
    for (int mi = 0; mi < 4; ++mi) aBase[mi] = (mi * 16 + l15) * WSTR + q * 8;
    #pragma unroll
    for (int ni = 0; ni < 4; ++ni) {
        int p = wave * 64 + ni * 16 + l15;
        int r = p >> 7, xx = p & 127;
        bBase[ni] = (r + 1) * RSTR + (xx + 1) * CSTR + q * 8;
    }

    const short* inB = in + (size_t)b * IH * IW * CH;
    const short* wtB = wt + (size_t)b * (64 * 9 * 64);

    for (int cc = 0; cc < 2; ++cc) {
        const int cin0 = cc * 32;
        // zero LDS pad columns 0 and 129
        if (t < 32) {
            int row = t >> 3, colsel = (t >> 2) & 1, c8 = (t & 3) * 8;
            int col = colsel ? 129 : 0;
            short8 z = {0,0,0,0,0,0,0,0};
            *(short8*)&in_tile[row * RSTR + col * CSTR + c8] = z;
        }
        // stage input: 4 rows x 128 cols x 32 cins
        #pragma unroll
        for (int i = 0; i < 8; ++i) {
            int s = i * 256 + t;
            int row = s >> 9;
            int col = (s >> 2) & 127;
            int c8 = (s & 3) * 8;
            int gy = y0 - 1 + row;
            short8 v = {0,0,0,0,0,0,0,0};
            if (gy >= 0 && gy < IH)
                v = *(const short8*)&inB[((size_t)gy * IW + col) * CH + cin0 + c8];
            *(short8*)&in_tile[row * RSTR + (col + 1) * CSTR + c8] = v;
        }
        // stage weights: 64 couts x 9 taps x 32 cins
        #pragma unroll
        for (int i = 0; i < 9; ++i) {
            int s = i * 256 + t;
            int cout = s / 36;
            int rem = s % 36;
            int tap = rem >> 2;
            int c8 = (rem & 3) * 8;
            short8 v = *(const short8*)&wtB[(cout * 9 + tap) * 64 + cin0 + c8];
            *(short8*)&w_tile[cout * WSTR + tap * 32 + c8] = v;
        }
        __syncthreads();

        #pragma unroll
        for (int tap = 0; tap < 9; ++tap) {
            const int dy = tap / 3 - 1, dx = tap % 3 - 1;
            const int koff = tap * 32;
            const int boff = dy * RSTR + dx * CSTR;
            short8 a[4], bb[4];
            #pragma unroll
            for (int mi = 0; mi < 4; ++mi)
                a[mi] = *(const short8*)&w_tile[aBase[mi] + koff];
            #pragma unroll
            for (int ni = 0; ni < 4; ++ni)
                bb[ni] = *(const short8*)&in_tile[bBase[ni] + boff];
            #pragma unroll
            for (int mi = 0; mi < 4; ++mi)
                #pragma unroll
                for (int ni = 0; ni < 4; ++ni)
                    acc[mi][ni] = __builtin_amdgcn_mfma_f32_16x16x32_bf16(
                        a[mi], bb[ni], acc[mi][ni], 0, 0, 0);
        }
        __syncthreads();
    }

    // epilogue: write bf16 NHWC + fused stats
    #pragma unroll
    for (int mi = 0; mi < 4; ++mi) {
        float psum[4] = {0.f,0.f,0.f,0.f};
        float psq[4]  = {0.f,0.f,0.f,0.f};
        #pragma unroll
        for (int ni = 0; ni < 4; ++ni) {
            int p = wave * 64 + ni * 16 + l15;
            int r = p >> 7, xx = p & 127;
            size_t base = (((size_t)b * IH + (y0 + r)) * IW + xx) * CH + mi * 16 + q * 4;
            short4v o;
            #pragma unroll
            for (int g = 0; g < 4; ++g) {
                float v = acc[mi][ni][g];
                o[g] = f2bf(v);
                psum[g] += v;
                psq[g]  += v * v;
            }
            *(short4v*)&out[base] = o;
        }
        #pragma unroll
        for (int g = 0; g < 4; ++g) {
            float s = psum[g], s2 = psq[g];
            #pragma unroll
            for (int off = 1; off < 16; off <<= 1) {
                s  += __shfl_xor(s,  off, 64);
                s2 += __shfl_xor(s2, off, 64);
            }
            if (l15 == 0) {
                int cout = mi * 16 + q * 4 + g;
                atomicAdd(&stats[(b * CH + cout) * 2 + 0], s);
                atomicAdd(&stats[(b * CH + cout) * 2 + 1], s2);
            }
        }
    }
}

// ---------------------------------------------------------------------------
// stats -> (scale, bias) per (b,c)
// ---------------------------------------------------------------------------
__global__ __launch_bounds__(256) void finalize_stats(const float* __restrict__ stats,
                                                      float* __restrict__ nrm) {
    int i = blockIdx.x * 256 + threadIdx.x;
    if (i < BATCH * CH) {
        float s = stats[i * 2], s2 = stats[i * 2 + 1];
        const float inv = 1.0f / (float)HW;
        float mean = s * inv;
        float var = s2 * inv - mean * mean;
        float scale = rsqrtf(var + 1e-5f);
        f32x2 sb = {scale, -mean * scale};
        ((f32x2*)nrm)[i] = sb;
    }
}

// ---------------------------------------------------------------------------
// h = leaky(norm(y1)), NHWC bf16 -> NHWC bf16
// total elements = 16*128*128*64 = 2^24; 8 per thread -> 2^21 threads = 8192 blocks
// ---------------------------------------------------------------------------
__global__ __launch_bounds__(256) void norm_leaky(const short* __restrict__ y,
                                                  const float* __restrict__ nrm,
                                                  short* __restrict__ h) {
    size_t idx = (size_t)blockIdx.x * 256 + threadIdx.x;
    if (idx >= (size_t)BATCH * HW * CH / 8) return;
    size_t e = idx * 8;
    int b  = (int)(e >> 20);     // HW*CH = 2^20 per batch
    int c0 = (int)(e & 63);
    const f32x2* nb = (const f32x2*)nrm + b * CH + c0;
    short8 v = *(const short8*)&y[e];
    short8 o;
    #pragma unroll
    for (int j = 0; j < 8; ++j) {
        f32x2 sb = nb[j];
        float f = sb.x * bf2f(v[j]) + sb.y;
        f = f >= 0.f ? f : 0.2f * f;
        o[j] = f2bf(f);
    }
    *(short8*)&h[e] = o;
}

// ---------------------------------------------------------------------------
// out = leaky(x + norm(y2)) : NHWC bf16 -> NCHW fp32 with LDS transpose
// ---------------------------------------------------------------------------
__global__ __launch_bounds__(256) void final_kernel(const float* __restrict__ x,
                                                    const short* __restrict__ y2,
                                                    const float* __restrict__ nrm,
                                                    float* __restrict__ out) {
    __shared__ float tile[64 * 65];
    const int x0 = blockIdx.x * 64;
    const int y  = blockIdx.y;
    const int b  = blockIdx.z;
    const int t  = threadIdx.x;
    const short* src = y2 + ((size_t)(b * IH + y) * IW + x0) * CH;
    const f32x2* nb = (const f32x2*)nrm + b * CH;
    #pragma unroll
    for (int i = 0; i < 2; ++i) {
        int s = i * 256 + t;
        int xx = s >> 3;
        int c0 = (s & 7) * 8;
        short8 v = *(const short8*)&src[xx * CH + c0];
        #pragma unroll
        for (int j = 0; j < 8; ++j) {
            f32x2 sb = nb[c0 + j];
            tile[(c0 + j) * 65 + xx] = sb.x * bf2f(v[j]) + sb.y;
        }
    }
    __syncthreads();
    #pragma unroll
    for (int i = 0; i < 4; ++i) {
        int lin = i * 1024 + t * 4;
        int c = lin >> 6;
        int xx = lin & 63;
        size_t g = ((size_t)(b * CH + c) * IH + y) * IW + x0 + xx;
        f32x4 xv = *(const f32x4*)&x[g];
        f32x4 o;
        #pragma unroll
        for (int k = 0; k < 4; ++k) {
            float f = xv[k] + tile[c * 65 + xx + k];
            o[k] = f >= 0.f ? f : 0.2f * f;
        }
        *(f32x4*)&out[g] = o;
    }
}

// ---------------------------------------------------------------------------
extern "C" void kernel_launch(void* const* d_in, const int* in_sizes, int n_in,
                              void* d_out, int out_size, void* d_ws, size_t ws_size,
                              hipStream_t stream) {
    const float* x  = (const float*)d_in[0];
    const float* w1 = (const float*)d_in[1];
    const float* w2 = (const float*)d_in[2];
    float* out = (float*)d_out;
    char* ws = (char*)d_ws;

    const size_t SZ_T = 33554432ull;           // one NHWC bf16 tensor (bytes)
    short* xbf = (short*)(ws);                 // reused as y2 after conv1
    short* y1  = (short*)(ws + SZ_T);
    short* h   = (short*)(ws + 2 * SZ_T);
    short* w1t = (short*)(ws + 3 * SZ_T);
    short* w2t = (short*)(ws + 3 * SZ_T + 1179648ull);
    float* stats1 = (float*)(ws + 3 * SZ_T + 2359296ull);
    float* stats2 = stats1 + BATCH * CH * 2;
    float* nrm1   = stats2 + BATCH * CH * 2;
    float* nrm2   = nrm1 + BATCH * CH * 2;
    short* y2 = xbf;

    if (ws_size < 3 * SZ_T + 2359296ull + 4 * BATCH * CH * 2 * sizeof(float)) return;

    hipMemsetAsync(stats1, 0, 2 * BATCH * CH * 2 * sizeof(float), stream);
    prep_x<<<BATCH * IH, 256, 0, stream>>>(x, xbf);
    prep_w<<<2 * WTOT / 1024, 256, 0, stream>>>(w1, w2, w1t, w2t);
    conv_kernel<<<dim3(64, 16), 256, 0, stream>>>(xbf, w1t, y1, stats1);
    finalize_stats<<<8, 256, 0, stream>>>(stats1, nrm1);
    norm_leaky<<<8192, 256, 0, stream>>>(y1, nrm1, h);   // 2^21 threads exactly
    conv_kernel<<<dim3(64, 16), 256, 0, stream>>>(h, w2t, y2, stats2);
    finalize_stats<<<8, 256, 0, stream>>>(stats2, nrm2);
    final_kernel<<<dim3(2, 128, 16), 256, 0, stream>>>(x, y2, nrm2, out);
}

// Round 3
// 445.908 us; speedup vs baseline: 1.0763x; 1.0763x over previous
//
#include <hip/hip_runtime.h>
#include <stdint.h>
#include <stddef.h>

#define BATCH 16
#define CH    64
#define IH    128
#define IW    128
#define HW    (IH*IW)

typedef __attribute__((ext_vector_type(8))) short short8;
typedef __attribute__((ext_vector_type(4))) short short4v;
typedef __attribute__((ext_vector_type(4))) float f32x4;
typedef __attribute__((ext_vector_type(2))) float f32x2;

__device__ __forceinline__ float bf2f(short s) {
    union { unsigned int u; float f; } v;
    v.u = ((unsigned int)(unsigned short)s) << 16;
    return v.f;
}
__device__ __forceinline__ short f2bf(float f) {
    union { float f; unsigned int u; } v; v.f = f;
    unsigned int r = v.u + 0x7fffu + ((v.u >> 16) & 1u);
    return (short)(r >> 16);
}
__device__ __forceinline__ void gld16(const void* g, void* l) {
    __builtin_amdgcn_global_load_lds(
        (const __attribute__((address_space(1))) void*)g,
        (__attribute__((address_space(3))) void*)l, 16, 0, 0);
}

// ---------------------------------------------------------------------------
// Layouts:
//   activations: [b][y][cc][x][cin32]   (cc = cin/32)  -- "NHWC32"
//   weights:     [b][cc][tap][cout][cin32]
// Both make conv staging a straight linear copy (global_load_lds-able) and
// all LDS fragment reads contiguous-1KB-per-wave (bank-conflict free).
// ---------------------------------------------------------------------------

// K0a: x NCHW fp32 -> NHWC32 bf16 (per-(b,y) row, LDS transpose)
__global__ __launch_bounds__(256) void prep_x(const float* __restrict__ x,
                                              short* __restrict__ xbf) {
    __shared__ float tile[CH * 129];
    const int b = blockIdx.x >> 7;
    const int y = blockIdx.x & 127;
    const int t = threadIdx.x;
    const float* src = x + (size_t)b * CH * HW + (size_t)y * IW;
    #pragma unroll
    for (int i = 0; i < 32; ++i) {
        int lin = i * 256 + t;
        int c = lin >> 7, xx = lin & 127;
        tile[c * 129 + xx] = src[(size_t)c * HW + xx];
    }
    __syncthreads();
    unsigned int* dst = (unsigned int*)(xbf) + ((size_t)(b * IH + y)) * 2 * 2048;
    #pragma unroll
    for (int j = 0; j < 16; ++j) {
        int lin = j * 256 + t;
        int c2 = lin & 31, xx = lin >> 5;          // c2: channel pair index
        unsigned int lo = (unsigned int)(unsigned short)f2bf(tile[(2 * c2) * 129 + xx]);
        unsigned int hi = (unsigned int)(unsigned short)f2bf(tile[(2 * c2 + 1) * 129 + xx]);
        // channels (2c2, 2c2+1) -> half cc = c2>>4, within-half u32 slot c2&15
        dst[(c2 >> 4) * 2048 + xx * 16 + (c2 & 15)] = lo | (hi << 16);
    }
}

// K0b: weights fp32 [b][co][ci][3][3] -> bf16 [b][cc][tap][cout][cin32]
// grid: 512 blocks x 256 (first 256 blocks = w1, rest = w2); tap-inner loop
// gives contiguous 36B-per-thread global reads.
__global__ __launch_bounds__(256) void prep_w(const float* __restrict__ w1,
                                              const float* __restrict__ w2,
                                              short* __restrict__ w1t,
                                              short* __restrict__ w2t) {
    int bid = blockIdx.x;
    const float* src = w1; short* dst = w1t;
    if (bid >= 256) { src = w2; dst = w2t; bid -= 256; }
    int gt = bid * 256 + threadIdx.x;       // [0, 65536) = (b, cc, cout, ci)
    int ci   = gt & 31;
    int cout = (gt >> 5) & 63;
    int cc   = (gt >> 11) & 1;
    int b    = gt >> 12;
    const float* s = src + ((size_t)(b * 64 + cout)) * 576 + (cc * 32 + ci) * 9;
    short* d = dst + ((size_t)(b * 2 + cc) * 9) * 2048 + cout * 32 + ci;
    #pragma unroll
    for (int tap = 0; tap < 9; ++tap)
        d[tap * 2048] = f2bf(s[tap]);
}

// ---------------------------------------------------------------------------
// Conv: implicit GEMM, M=64 couts x N=256 px (2 rows), K=576.
// Staging via global_load_lds(16B); conflict-free LDS; fused stats atomics.
// ---------------------------------------------------------------------------
#define RSTR 4160                 // shorts per in_tile row = 130 cols * 32 cin
#define IN_TILE_SH (4 * RSTR)     // 16640 shorts = 33280 B
#define W_TILE_SH  (9 * 64 * 32)  // 18432 shorts = 36864 B

__global__ __launch_bounds__(256) void conv_kernel(
    const short* __restrict__ in, const short* __restrict__ wt,
    short* __restrict__ out, float* __restrict__ stats) {

    __shared__ short in_tile[IN_TILE_SH];
    __shared__ short w_tile[W_TILE_SH];

    const int b    = blockIdx.y;
    const int y0   = blockIdx.x * 2;
    const int t    = threadIdx.x;
    const int lane = t & 63;
    const int wave = t >> 6;
    const int l15  = lane & 15;
    const int q    = lane >> 4;

    const f32x4 zero4 = {0.f, 0.f, 0.f, 0.f};
    f32x4 acc[4][4];
    #pragma unroll
    for (int mi = 0; mi < 4; ++mi)
        #pragma unroll
        for (int ni = 0; ni < 4; ++ni) acc[mi][ni] = zero4;

    // zero halo pad columns (col 0, col 129) of all 4 rows, once.
    if (t < 32) {
        int r = t >> 3, csel = (t >> 2) & 1, k = t & 3;
        short8 z = {0,0,0,0,0,0,0,0};
        *(short8*)&in_tile[r * RSTR + (csel ? 129 * 32 : 0) + k * 8] = z;
    }

    int aBase[4], bBase[4];
    #pragma unroll
    for (int mi = 0; mi < 4; ++mi) aBase[mi] = (mi * 16 + l15) * 32 + q * 8;
    #pragma unroll
    for (int ni = 0; ni < 4; ++ni) {
        int p = wave * 64 + ni * 16 + l15;
        int r = p >> 7, xx = p & 127;
        bBase[ni] = (r + 1) * RSTR + (xx + 1) * 32 + q * 8;
    }

    const short* inB = in + (size_t)b * (IH * 2 * 4096);   // [y][cc][x][32]
    const short* wtB = wt + (size_t)b * (2 * W_TILE_SH);

    for (int cc = 0; cc < 2; ++cc) {
        // ---- stage input: 4 rows (halo), each an 8192-B linear copy ----
        #pragma unroll
        for (int r = 0; r < 4; ++r) {
            int gy = y0 - 1 + r;
            if (gy >= 0 && gy < IH) {
                const short* src = inB + (size_t)(gy * 2 + cc) * 4096;
                #pragma unroll
                for (int i = 0; i < 2; ++i) {
                    int chunk = i * 256 + t;
                    gld16(src + chunk * 8, &in_tile[r * RSTR + 32 + chunk * 8]);
                }
            } else {
                short8 z = {0,0,0,0,0,0,0,0};
                #pragma unroll
                for (int i = 0; i < 2; ++i) {
                    int chunk = i * 256 + t;
                    *(short8*)&in_tile[r * RSTR + 32 + chunk * 8] = z;
                }
            }
        }
        // ---- stage weights: 36864-B linear copy, 9 chunks/thread ----
        {
            const short* wsrc = wtB + (size_t)cc * W_TILE_SH;
            #pragma unroll
            for (int i = 0; i < 9; ++i) {
                int chunk = i * 256 + t;
                gld16(wsrc + chunk * 8, &w_tile[chunk * 8]);
            }
        }
        __syncthreads();

        #pragma unroll
        for (int tap = 0; tap < 9; ++tap) {
            const int dy = tap / 3 - 1, dx = tap % 3 - 1;
            const int koff = tap * 2048;            // tap*64*32
            const int boff = dy * RSTR + dx * 32;
            short8 a[4], bb[4];
            #pragma unroll
            for (int mi = 0; mi < 4; ++mi)
                a[mi] = *(const short8*)&w_tile[aBase[mi] + koff];
            #pragma unroll
            for (int ni = 0; ni < 4; ++ni)
                bb[ni] = *(const short8*)&in_tile[bBase[ni] + boff];
            #pragma unroll
            for (int mi = 0; mi < 4; ++mi)
                #pragma unroll
                for (int ni = 0; ni < 4; ++ni)
                    acc[mi][ni] = __builtin_amdgcn_mfma_f32_16x16x32_bf16(
                        a[mi], bb[ni], acc[mi][ni], 0, 0, 0);
        }
        __syncthreads();
    }

    // epilogue: write bf16 NHWC32 + fused stats
    #pragma unroll
    for (int mi = 0; mi < 4; ++mi) {
        float psum[4] = {0.f,0.f,0.f,0.f};
        float psq[4]  = {0.f,0.f,0.f,0.f};
        #pragma unroll
        for (int ni = 0; ni < 4; ++ni) {
            int p = wave * 64 + ni * 16 + l15;
            int r = p >> 7, xx = p & 127;
            size_t base = ((((size_t)b * IH + (y0 + r)) * 2 + (mi >> 1)) * IW + xx) * 32
                          + (mi & 1) * 16 + q * 4;
            short4v o;
            #pragma unroll
            for (int g = 0; g < 4; ++g) {
                float v = acc[mi][ni][g];
                o[g] = f2bf(v);
                psum[g] += v;
                psq[g]  += v * v;
            }
            *(short4v*)&out[base] = o;
        }
        #pragma unroll
        for (int g = 0; g < 4; ++g) {
            float s = psum[g], s2 = psq[g];
            #pragma unroll
            for (int off = 1; off < 16; off <<= 1) {
                s  += __shfl_xor(s,  off, 64);
                s2 += __shfl_xor(s2, off, 64);
            }
            if (l15 == 0) {
                int cout = mi * 16 + q * 4 + g;
                atomicAdd(&stats[(b * CH + cout) * 2 + 0], s);
                atomicAdd(&stats[(b * CH + cout) * 2 + 1], s2);
            }
        }
    }
}

// ---------------------------------------------------------------------------
__global__ __launch_bounds__(256) void finalize_stats(const float* __restrict__ stats,
                                                      float* __restrict__ nrm) {
    int i = blockIdx.x * 256 + threadIdx.x;
    if (i < BATCH * CH) {
        float s = stats[i * 2], s2 = stats[i * 2 + 1];
        const float inv = 1.0f / (float)HW;
        float mean = s * inv;
        float var = s2 * inv - mean * mean;
        float scale = rsqrtf(var + 1e-5f);
        f32x2 sb = {scale, -mean * scale};
        ((f32x2*)nrm)[i] = sb;
    }
}

// ---------------------------------------------------------------------------
// h = leaky(norm(y1)), NHWC32 bf16 -> NHWC32 bf16. 2^24 elems, 8/thread.
// ---------------------------------------------------------------------------
__global__ __launch_bounds__(256) void norm_leaky(const short* __restrict__ y,
                                                  const float* __restrict__ nrm,
                                                  short* __restrict__ h) {
    size_t idx = (size_t)blockIdx.x * 256 + threadIdx.x;
    if (idx >= (size_t)BATCH * HW * CH / 8) return;
    size_t e = idx * 8;
    int b  = (int)(e >> 20);
    int cc = (int)(e >> 12) & 1;
    int c0 = (int)(e & 31);
    const f32x2* nb = (const f32x2*)nrm + b * CH + cc * 32 + c0;
    short8 v = *(const short8*)&y[e];
    short8 o;
    #pragma unroll
    for (int j = 0; j < 8; ++j) {
        f32x2 sb = nb[j];
        float f = sb.x * bf2f(v[j]) + sb.y;
        f = f >= 0.f ? f : 0.2f * f;
        o[j] = f2bf(f);
    }
    *(short8*)&h[e] = o;
}

// ---------------------------------------------------------------------------
// out = leaky(x + norm(y2)) : NHWC32 bf16 -> NCHW fp32, LDS transpose
// ---------------------------------------------------------------------------
__global__ __launch_bounds__(256) void final_kernel(const float* __restrict__ x,
                                                    const short* __restrict__ y2,
                                                    const float* __restrict__ nrm,
                                                    float* __restrict__ out) {
    __shared__ float tile[64 * 65];
    const int x0 = blockIdx.x * 64;
    const int y  = blockIdx.y;
    const int b  = blockIdx.z;
    const int t  = threadIdx.x;
    const f32x2* nb = (const f32x2*)nrm + b * CH;
    const size_t rowb = ((size_t)(b * IH + y)) * 2 * 4096;  // [cc][x][32]
    #pragma unroll
    for (int i = 0; i < 2; ++i) {
        int s = i * 256 + t;
        int xx = s >> 3;
        int c0 = (s & 7) * 8;
        int cc = c0 >> 5, cl = c0 & 31;
        short8 v = *(const short8*)&y2[rowb + (size_t)cc * 4096 + (x0 + xx) * 32 + cl];
        #pragma unroll
        for (int j = 0; j < 8; ++j) {
            f32x2 sb = nb[c0 + j];
            tile[(c0 + j) * 65 + xx] = sb.x * bf2f(v[j]) + sb.y;
        }
    }
    __syncthreads();
    #pragma unroll
    for (int i = 0; i < 4; ++i) {
        int lin = i * 1024 + t * 4;
        int c = lin >> 6;
        int xx = lin & 63;
        size_t g = ((size_t)(b * CH + c) * IH + y) * IW + x0 + xx;
        f32x4 xv = *(const f32x4*)&x[g];
        f32x4 o;
        #pragma unroll
        for (int k = 0; k < 4; ++k) {
            float f = xv[k] + tile[c * 65 + xx + k];
            o[k] = f >= 0.f ? f : 0.2f * f;
        }
        *(f32x4*)&out[g] = o;
    }
}

// ---------------------------------------------------------------------------
extern "C" void kernel_launch(void* const* d_in, const int* in_sizes, int n_in,
                              void* d_out, int out_size, void* d_ws, size_t ws_size,
                              hipStream_t stream) {
    const float* x  = (const float*)d_in[0];
    const float* w1 = (const float*)d_in[1];
    const float* w2 = (const float*)d_in[2];
    float* out = (float*)d_out;
    char* ws = (char*)d_ws;

    const size_t SZ_T = 33554432ull;           // one NHWC32 bf16 tensor (bytes)
    short* xbf = (short*)(ws);                 // reused as y2 after conv1
    short* y1  = (short*)(ws + SZ_T);
    short* h   = (short*)(ws + 2 * SZ_T);
    short* w1t = (short*)(ws + 3 * SZ_T);
    short* w2t = (short*)(ws + 3 * SZ_T + 1179648ull);
    float* stats1 = (float*)(ws + 3 * SZ_T + 2359296ull);
    float* stats2 = stats1 + BATCH * CH * 2;
    float* nrm1   = stats2 + BATCH * CH * 2;
    float* nrm2   = nrm1 + BATCH * CH * 2;
    short* y2 = xbf;

    if (ws_size < 3 * SZ_T + 2359296ull + 4 * BATCH * CH * 2 * sizeof(float)) return;

    hipMemsetAsync(stats1, 0, 2 * BATCH * CH * 2 * sizeof(float), stream);
    prep_x<<<BATCH * IH, 256, 0, stream>>>(x, xbf);
    prep_w<<<512, 256, 0, stream>>>(w1, w2, w1t, w2t);
    conv_kernel<<<dim3(64, 16), 256, 0, stream>>>(xbf, w1t, y1, stats1);
    finalize_stats<<<8, 256, 0, stream>>>(stats1, nrm1);
    norm_leaky<<<8192, 256, 0, stream>>>(y1, nrm1, h);
    conv_kernel<<<dim3(64, 16), 256, 0, stream>>>(h, w2t, y2, stats2);
    finalize_stats<<<8, 256, 0, stream>>>(stats2, nrm2);
    final_kernel<<<dim3(2, 128, 16), 256, 0, stream>>>(x, y2, nrm2, out);
}

// Round 4
// 428.592 us; speedup vs baseline: 1.1197x; 1.0404x over previous
//
#include <hip/hip_runtime.h>
#include <stdint.h>
#include <stddef.h>

#define BATCH 16
#define CH    64
#define IH    128
#define IW    128
#define HW    (IH*IW)

// Padded activation layout: [b][yp 0..129][cc 0..1][xp 0..129][cin32]
#define PROW 8320            // shorts per padded row (2*130*32)
#define PB   1081600         // shorts per batch (130*PROW)

typedef __attribute__((ext_vector_type(8))) short short8;
typedef __attribute__((ext_vector_type(4))) short short4v;
typedef __attribute__((ext_vector_type(4))) float f32x4;
typedef __attribute__((ext_vector_type(2))) float f32x2;

__device__ __forceinline__ float bf2f(short s) {
    union { unsigned int u; float f; } v;
    v.u = ((unsigned int)(unsigned short)s) << 16;
    return v.f;
}
__device__ __forceinline__ short f2bf(float f) {
    union { float f; unsigned int u; } v; v.f = f;
    unsigned int r = v.u + 0x7fffu + ((v.u >> 16) & 1u);
    return (short)(r >> 16);
}
__device__ __forceinline__ void gld16(const void* g, void* l) {
    __builtin_amdgcn_global_load_lds(
        (const __attribute__((address_space(1))) void*)g,
        (__attribute__((address_space(3))) void*)l, 16, 0, 0);
}

// ---------------------------------------------------------------------------
// Zero the halo pads of both padded activation buffers (ws is re-poisoned
// to 0xAA before every call, so pads must be re-zeroed each launch).
// grid 32: bid&1 selects buffer, bid>>1 selects batch.
// ---------------------------------------------------------------------------
__global__ __launch_bounds__(256) void pad_zero(short* __restrict__ xpad,
                                                short* __restrict__ hpad) {
    int bid = blockIdx.x;
    short* p = ((bid & 1) ? hpad : xpad) + (size_t)(bid >> 1) * PB;
    const short8 z = {0,0,0,0,0,0,0,0};
    #pragma unroll
    for (int i = 0; i < 17; ++i) {
        int s = i * 256 + threadIdx.x;
        if (s >= 4128) break;
        if (s < 2080) {                       // padded rows 0 and 129 (full)
            int row = (s < 1040) ? 0 : 129;
            int o = (s < 1040 ? s : s - 1040) * 8;
            *(short8*)&p[(size_t)row * PROW + o] = z;
        } else {                              // cols 0 and 129 of rows 1..128
            int u = s - 2080;                 // [0,2048)
            int k = u & 3, col = (u >> 2) & 1, cc = (u >> 3) & 1, pr = (u >> 4) + 1;
            *(short8*)&p[(size_t)pr * PROW + cc * 4160 + (col ? 129 * 32 : 0) + k * 8] = z;
        }
    }
}

// ---------------------------------------------------------------------------
// K0a: x NCHW fp32 -> padded NHWC32 bf16 interior (per-(b,y) row, LDS transpose)
// ---------------------------------------------------------------------------
__global__ __launch_bounds__(256) void prep_x(const float* __restrict__ x,
                                              short* __restrict__ xpad) {
    __shared__ float tile[CH * 129];
    const int b = blockIdx.x >> 7;
    const int y = blockIdx.x & 127;
    const int t = threadIdx.x;
    const float* src = x + (size_t)b * CH * HW + (size_t)y * IW;
    #pragma unroll
    for (int i = 0; i < 32; ++i) {
        int lin = i * 256 + t;
        int c = lin >> 7, xx = lin & 127;
        tile[c * 129 + xx] = src[(size_t)c * HW + xx];
    }
    __syncthreads();
    unsigned int* dst = (unsigned int*)(xpad) + (size_t)b * (PB / 2) + (size_t)(y + 1) * (PROW / 2);
    #pragma unroll
    for (int j = 0; j < 16; ++j) {
        int lin = j * 256 + t;
        int c2 = lin & 31, xx = lin >> 5;
        unsigned int lo = (unsigned int)(unsigned short)f2bf(tile[(2 * c2) * 129 + xx]);
        unsigned int hi = (unsigned int)(unsigned short)f2bf(tile[(2 * c2 + 1) * 129 + xx]);
        dst[(c2 >> 4) * 2080 + (xx + 1) * 16 + (c2 & 15)] = lo | (hi << 16);
    }
}

// ---------------------------------------------------------------------------
// K0b: weights fp32 [b][co][ci][3][3] -> bf16 [b][cc][tap][cout][cin32]
// ---------------------------------------------------------------------------
__global__ __launch_bounds__(256) void prep_w(const float* __restrict__ w1,
                                              const float* __restrict__ w2,
                                              short* __restrict__ w1t,
                                              short* __restrict__ w2t) {
    int bid = blockIdx.x;
    const float* src = w1; short* dst = w1t;
    if (bid >= 256) { src = w2; dst = w2t; bid -= 256; }
    int gt = bid * 256 + threadIdx.x;       // (b, cc, cout, ci)
    int ci   = gt & 31;
    int cout = (gt >> 5) & 63;
    int cc   = (gt >> 11) & 1;
    int b    = gt >> 12;
    const float* s = src + ((size_t)(b * 64 + cout)) * 576 + (cc * 32 + ci) * 9;
    short* d = dst + ((size_t)(b * 2 + cc) * 9) * 2048 + cout * 32 + ci;
    #pragma unroll
    for (int tap = 0; tap < 9; ++tap)
        d[tap * 2048] = f2bf(s[tap]);
}

// ---------------------------------------------------------------------------
// Conv: weights resident in LDS (one barrier); activation B-fragments loaded
// DIRECTLY from the padded global buffer (1 KB coalesced per wave-load).
// Block = (b, 4 output rows as 2 y-tiles). M=64 couts, N=256 px per y-tile.
// grid dim3(32,16) = 512 blocks = exactly 2 per CU.
// ---------------------------------------------------------------------------
__global__ __launch_bounds__(256) void conv_kernel(
    const short* __restrict__ in, const short* __restrict__ wt,
    short* __restrict__ out, float* __restrict__ stats) {

    __shared__ short w_tile[36864];          // 2cc * 9tap * 64cout * 32cin = 73728 B

    const int b     = blockIdx.y;
    const int ybase = blockIdx.x * 4;
    const int t     = threadIdx.x;
    const int lane  = t & 63;
    const int wave  = t >> 6;
    const int l15   = lane & 15;
    const int q     = lane >> 4;

    // stage all weights once (4608 16-B chunks)
    const short* wtB = wt + (size_t)b * 36864;
    #pragma unroll
    for (int i = 0; i < 18; ++i) {
        int chunk = i * 256 + t;
        gld16(wtB + chunk * 8, &w_tile[chunk * 8]);
    }
    __syncthreads();

    const short* inB = in + (size_t)b * PB;
    const int laneoff = l15 * 32 + q * 8;    // px*64B + quad*16B within a row
    const int r  = wave >> 1;                // waves 0,1 -> out row 0; 2,3 -> row 1
    const int xw = (wave & 1) * 64;          // wave's x base

    int aBase[4];
    #pragma unroll
    for (int mi = 0; mi < 4; ++mi) aBase[mi] = (mi * 16 + l15) * 32 + q * 8;

    for (int yt = 0; yt < 2; ++yt) {
        const int y0 = ybase + yt * 2;
        const f32x4 zero4 = {0.f, 0.f, 0.f, 0.f};
        f32x4 acc[4][4];
        #pragma unroll
        for (int mi = 0; mi < 4; ++mi)
            #pragma unroll
            for (int ni = 0; ni < 4; ++ni) acc[mi][ni] = zero4;

        #pragma unroll
        for (int cc = 0; cc < 2; ++cc) {
            #pragma unroll
            for (int tap = 0; tap < 9; ++tap) {
                const int dy = tap / 3, dx = tap % 3;
                const short* bsrc = inB + (size_t)(y0 + r + dy) * PROW
                                    + cc * 4160 + dx * 32 + laneoff;
                short8 bb[4], a[4];
                #pragma unroll
                for (int ni = 0; ni < 4; ++ni)
                    bb[ni] = *(const short8*)&bsrc[(xw + ni * 16) * 32];
                #pragma unroll
                for (int mi = 0; mi < 4; ++mi)
                    a[mi] = *(const short8*)&w_tile[(cc * 9 + tap) * 2048 + aBase[mi]];
                #pragma unroll
                for (int mi = 0; mi < 4; ++mi)
                    #pragma unroll
                    for (int ni = 0; ni < 4; ++ni)
                        acc[mi][ni] = __builtin_amdgcn_mfma_f32_16x16x32_bf16(
                            a[mi], bb[ni], acc[mi][ni], 0, 0, 0);
            }
        }

        // epilogue: write bf16 into padded interior + fused stats
        #pragma unroll
        for (int mi = 0; mi < 4; ++mi) {
            float psum[4] = {0.f,0.f,0.f,0.f};
            float psq[4]  = {0.f,0.f,0.f,0.f};
            #pragma unroll
            for (int ni = 0; ni < 4; ++ni) {
                int xx = xw + ni * 16 + l15;
                size_t base = (size_t)b * PB + (size_t)(1 + y0 + r) * PROW
                              + (mi >> 1) * 4160 + (1 + xx) * 32
                              + (mi & 1) * 16 + q * 4;
                short4v o;
                #pragma unroll
                for (int g = 0; g < 4; ++g) {
                    float v = acc[mi][ni][g];
                    o[g] = f2bf(v);
                    psum[g] += v;
                    psq[g]  += v * v;
                }
                *(short4v*)&out[base] = o;
            }
            #pragma unroll
            for (int g = 0; g < 4; ++g) {
                float s = psum[g], s2 = psq[g];
                #pragma unroll
                for (int off = 1; off < 16; off <<= 1) {
                    s  += __shfl_xor(s,  off, 64);
                    s2 += __shfl_xor(s2, off, 64);
                }
                if (l15 == 0) {
                    int cout = mi * 16 + q * 4 + g;
                    atomicAdd(&stats[(b * CH + cout) * 2 + 0], s);
                    atomicAdd(&stats[(b * CH + cout) * 2 + 1], s2);
                }
            }
        }
    }
}

// ---------------------------------------------------------------------------
__global__ __launch_bounds__(256) void finalize_stats(const float* __restrict__ stats,
                                                      float* __restrict__ nrm) {
    int i = blockIdx.x * 256 + threadIdx.x;
    if (i < BATCH * CH) {
        float s = stats[i * 2], s2 = stats[i * 2 + 1];
        const float inv = 1.0f / (float)HW;
        float mean = s * inv;
        float var = s2 * inv - mean * mean;
        float scale = rsqrtf(var + 1e-5f);
        f32x2 sb = {scale, -mean * scale};
        ((f32x2*)nrm)[i] = sb;
    }
}

// ---------------------------------------------------------------------------
// h = leaky(norm(y1)) IN PLACE on the padded buffer interior.
// grid 2048 = (b,y) rows; 1024 short8 per row, 4 per thread.
// ---------------------------------------------------------------------------
__global__ __launch_bounds__(256) void norm_leaky(short* __restrict__ hpad,
                                                  const float* __restrict__ nrm) {
    const int bid = blockIdx.x;
    const int b = bid >> 7, y = bid & 127;
    short* row = hpad + (size_t)b * PB + (size_t)(y + 1) * PROW;
    const int t = threadIdx.x;
    #pragma unroll
    for (int i = 0; i < 4; ++i) {
        int s = i * 256 + t;
        int c8 = s & 3, xx = (s >> 2) & 127, cc = s >> 9;
        short* p = row + cc * 4160 + (xx + 1) * 32 + c8 * 8;
        const f32x2* nb = (const f32x2*)nrm + b * CH + cc * 32 + c8 * 8;
        short8 v = *(const short8*)p;
        short8 o;
        #pragma unroll
        for (int j = 0; j < 8; ++j) {
            f32x2 sb = nb[j];
            float f = sb.x * bf2f(v[j]) + sb.y;
            f = f >= 0.f ? f : 0.2f * f;
            o[j] = f2bf(f);
        }
        *(short8*)p = o;
    }
}

// ---------------------------------------------------------------------------
// out = leaky(x + norm(y2)) : padded NHWC32 bf16 -> NCHW fp32, LDS transpose
// ---------------------------------------------------------------------------
__global__ __launch_bounds__(256) void final_kernel(const float* __restrict__ x,
                                                    const short* __restrict__ y2,
                                                    const float* __restrict__ nrm,
                                                    float* __restrict__ out) {
    __shared__ float tile[64 * 65];
    const int x0 = blockIdx.x * 64;
    const int y  = blockIdx.y;
    const int b  = blockIdx.z;
    const int t  = threadIdx.x;
    const f32x2* nb = (const f32x2*)nrm + b * CH;
    const size_t rowb = (size_t)b * PB + (size_t)(y + 1) * PROW;
    #pragma unroll
    for (int i = 0; i < 2; ++i) {
        int s = i * 256 + t;
        int xx = s >> 3;
        int c0 = (s & 7) * 8;
        int cc = c0 >> 5, cl = c0 & 31;
        short8 v = *(const short8*)&y2[rowb + cc * 4160 + (size_t)(x0 + xx + 1) * 32 + cl];
        #pragma unroll
        for (int j = 0; j < 8; ++j) {
            f32x2 sb = nb[c0 + j];
            tile[(c0 + j) * 65 + xx] = sb.x * bf2f(v[j]) + sb.y;
        }
    }
    __syncthreads();
    #pragma unroll
    for (int i = 0; i < 4; ++i) {
        int lin = i * 1024 + t * 4;
        int c = lin >> 6;
        int xx = lin & 63;
        size_t g = ((size_t)(b * CH + c) * IH + y) * IW + x0 + xx;
        f32x4 xv = *(const f32x4*)&x[g];
        f32x4 o;
        #pragma unroll
        for (int k = 0; k < 4; ++k) {
            float f = xv[k] + tile[c * 65 + xx + k];
            o[k] = f >= 0.f ? f : 0.2f * f;
        }
        *(f32x4*)&out[g] = o;
    }
}

// ---------------------------------------------------------------------------
extern "C" void kernel_launch(void* const* d_in, const int* in_sizes, int n_in,
                              void* d_out, int out_size, void* d_ws, size_t ws_size,
                              hipStream_t stream) {
    const float* x  = (const float*)d_in[0];
    const float* w1 = (const float*)d_in[1];
    const float* w2 = (const float*)d_in[2];
    float* out = (float*)d_out;
    char* ws = (char*)d_ws;

    const size_t SZ_PAD = 34611200ull;         // one padded NHWC32 bf16 tensor
    short* xpad = (short*)(ws);                // x (conv1 in), later y2 (conv2 out)
    short* hpad = (short*)(ws + SZ_PAD);       // y1 / h (conv1 out, conv2 in)
    short* w1t  = (short*)(ws + 2 * SZ_PAD);
    short* w2t  = (short*)(ws + 2 * SZ_PAD + 1179648ull);
    float* stats1 = (float*)(ws + 2 * SZ_PAD + 2359296ull);
    float* stats2 = stats1 + BATCH * CH * 2;
    float* nrm1   = stats2 + BATCH * CH * 2;
    float* nrm2   = nrm1 + BATCH * CH * 2;

    if (ws_size < 2 * SZ_PAD + 2359296ull + 4 * BATCH * CH * 2 * sizeof(float)) return;

    hipMemsetAsync(stats1, 0, 2 * BATCH * CH * 2 * sizeof(float), stream);
    pad_zero<<<32, 256, 0, stream>>>(xpad, hpad);
    prep_x<<<BATCH * IH, 256, 0, stream>>>(x, xpad);
    prep_w<<<512, 256, 0, stream>>>(w1, w2, w1t, w2t);
    conv_kernel<<<dim3(32, 16), 256, 0, stream>>>(xpad, w1t, hpad, stats1);
    finalize_stats<<<8, 256, 0, stream>>>(stats1, nrm1);
    norm_leaky<<<2048, 256, 0, stream>>>(hpad, nrm1);
    conv_kernel<<<dim3(32, 16), 256, 0, stream>>>(hpad, w2t, xpad, stats2);
    finalize_stats<<<8, 256, 0, stream>>>(stats2, nrm2);
    final_kernel<<<dim3(2, 128, 16), 256, 0, stream>>>(x, xpad, nrm2, out);
}

// Round 5
// 303.951 us; speedup vs baseline: 1.5789x; 1.4101x over previous
//
#include <hip/hip_runtime.h>
#include <stdint.h>
#include <stddef.h>

#define BATCH 16
#define CH    64
#define IH    128
#define IW    128
#define HW    (IH*IW)

// Padded activation layout: [b][yp 0..129][cc 0..1][xp 0..129][cin32]
#define PROW 8320            // shorts per padded row (2*130*32)
#define PB   1081600         // shorts per batch (130*PROW)

typedef __attribute__((ext_vector_type(8))) short short8;
typedef __attribute__((ext_vector_type(4))) short short4v;
typedef __attribute__((ext_vector_type(4))) float f32x4;
typedef __attribute__((ext_vector_type(2))) float f32x2;

__device__ __forceinline__ float bf2f(short s) {
    union { unsigned int u; float f; } v;
    v.u = ((unsigned int)(unsigned short)s) << 16;
    return v.f;
}
__device__ __forceinline__ short f2bf(float f) {
    union { float f; unsigned int u; } v; v.f = f;
    unsigned int r = v.u + 0x7fffu + ((v.u >> 16) & 1u);
    return (short)(r >> 16);
}

// ---------------------------------------------------------------------------
// Zero the halo pads of both padded activation buffers.
// ---------------------------------------------------------------------------
__global__ __launch_bounds__(256) void pad_zero(short* __restrict__ xpad,
                                                short* __restrict__ hpad) {
    int bid = blockIdx.x;
    short* p = ((bid & 1) ? hpad : xpad) + (size_t)(bid >> 1) * PB;
    const short8 z = {0,0,0,0,0,0,0,0};
    #pragma unroll
    for (int i = 0; i < 17; ++i) {
        int s = i * 256 + threadIdx.x;
        if (s >= 4128) break;
        if (s < 2080) {                       // padded rows 0 and 129 (full)
            int row = (s < 1040) ? 0 : 129;
            int o = (s < 1040 ? s : s - 1040) * 8;
            *(short8*)&p[(size_t)row * PROW + o] = z;
        } else {                              // cols 0 and 129 of rows 1..128
            int u = s - 2080;                 // [0,2048)
            int k = u & 3, col = (u >> 2) & 1, cc = (u >> 3) & 1, pr = (u >> 4) + 1;
            *(short8*)&p[(size_t)pr * PROW + cc * 4160 + (col ? 129 * 32 : 0) + k * 8] = z;
        }
    }
}

// ---------------------------------------------------------------------------
// K0a: x NCHW fp32 -> padded NHWC32 bf16 interior (per-(b,y) row, LDS transpose)
// ---------------------------------------------------------------------------
__global__ __launch_bounds__(256) void prep_x(const float* __restrict__ x,
                                              short* __restrict__ xpad) {
    __shared__ float tile[CH * 129];
    const int b = blockIdx.x >> 7;
    const int y = blockIdx.x & 127;
    const int t = threadIdx.x;
    const float* src = x + (size_t)b * CH * HW + (size_t)y * IW;
    #pragma unroll
    for (int i = 0; i < 32; ++i) {
        int lin = i * 256 + t;
        int c = lin >> 7, xx = lin & 127;
        tile[c * 129 + xx] = src[(size_t)c * HW + xx];
    }
    __syncthreads();
    unsigned int* dst = (unsigned int*)(xpad) + (size_t)b * (PB / 2) + (size_t)(y + 1) * (PROW / 2);
    #pragma unroll
    for (int j = 0; j < 16; ++j) {
        int lin = j * 256 + t;
        int c2 = lin & 31, xx = lin >> 5;
        unsigned int lo = (unsigned int)(unsigned short)f2bf(tile[(2 * c2) * 129 + xx]);
        unsigned int hi = (unsigned int)(unsigned short)f2bf(tile[(2 * c2 + 1) * 129 + xx]);
        dst[(c2 >> 4) * 2080 + (xx + 1) * 16 + (c2 & 15)] = lo | (hi << 16);
    }
}

// ---------------------------------------------------------------------------
// K0b: weights fp32 [b][co][ci][3][3] -> bf16 [b][cc][tap][cout][cin32]
// ---------------------------------------------------------------------------
__global__ __launch_bounds__(256) void prep_w(const float* __restrict__ w1,
                                              const float* __restrict__ w2,
                                              short* __restrict__ w1t,
                                              short* __restrict__ w2t) {
    int bid = blockIdx.x;
    const float* src = w1; short* dst = w1t;
    if (bid >= 256) { src = w2; dst = w2t; bid -= 256; }
    int gt = bid * 256 + threadIdx.x;       // (b, cc, cout, ci)
    int ci   = gt & 31;
    int cout = (gt >> 5) & 63;
    int cc   = (gt >> 11) & 1;
    int b    = gt >> 12;
    const float* s = src + ((size_t)(b * 64 + cout)) * 576 + (cc * 32 + ci) * 9;
    short* d = dst + ((size_t)(b * 2 + cc) * 9) * 2048 + cout * 32 + ci;
    #pragma unroll
    for (int tap = 0; tap < 9; ++tap)
        d[tap * 2048] = f2bf(s[tap]);
}

// ---------------------------------------------------------------------------
// Conv: zero-LDS, latency-hiding-by-occupancy implicit GEMM.
// Block = 4 waves = one output row: 64 cout x 128 px.
// Wave: (coutHalf=wave&1, pxHalf=wave>>1) -> 32 cout x 64 px, acc 2x4 f32x4.
// A-frags (weights) and B-frags (padded activations) both direct global loads,
// each a contiguous 1 KB per wave (L1/L2-resident). No barriers, no atomics.
// grid dim3(128, 16) = 2048 blocks.
// ---------------------------------------------------------------------------
__global__ __launch_bounds__(256, 4) void conv_kernel(
    const short* __restrict__ in, const short* __restrict__ wt,
    short* __restrict__ out,
    float* __restrict__ part_s, float* __restrict__ part_q) {

    const int b    = blockIdx.y;
    const int y0   = blockIdx.x;             // output row
    const int t    = threadIdx.x;
    const int lane = t & 63;
    const int wave = t >> 6;
    const int l15  = lane & 15;
    const int q    = lane >> 4;
    const int ch   = wave & 1;               // cout half
    const int ph   = wave >> 1;              // px half
    const int xb   = ph * 64;

    const short* wgl = wt + (size_t)b * 36864;
    const short* inB = in + (size_t)b * PB;
    const int aoff = (ch * 32 + l15) * 32 + q * 8;
    const int boff = (xb + l15) * 32 + q * 8;

    const f32x4 zero4 = {0.f, 0.f, 0.f, 0.f};
    f32x4 acc[2][4];
    #pragma unroll
    for (int mi = 0; mi < 2; ++mi)
        #pragma unroll
        for (int ni = 0; ni < 4; ++ni) acc[mi][ni] = zero4;

    #pragma unroll
    for (int cc = 0; cc < 2; ++cc) {
        #pragma unroll
        for (int tap = 0; tap < 9; ++tap) {
            const int dy = tap / 3, dx = tap % 3;
            const short* arow = wgl + (cc * 9 + tap) * 2048 + aoff;
            const short* brow = inB + (size_t)(y0 + dy) * PROW + cc * 4160 + dx * 32 + boff;
            short8 a[2], bb[4];
            #pragma unroll
            for (int mi = 0; mi < 2; ++mi)
                a[mi] = *(const short8*)&arow[mi * 512];
            #pragma unroll
            for (int ni = 0; ni < 4; ++ni)
                bb[ni] = *(const short8*)&brow[ni * 512];
            #pragma unroll
            for (int mi = 0; mi < 2; ++mi)
                #pragma unroll
                for (int ni = 0; ni < 4; ++ni)
                    acc[mi][ni] = __builtin_amdgcn_mfma_f32_16x16x32_bf16(
                        a[mi], bb[ni], acc[mi][ni], 0, 0, 0);
        }
    }

    // epilogue: write bf16 into padded interior + per-wave partial stats
    const int pbase = ((b * 128 + y0) * 2 + ph) * 64 + ch * 32;
    #pragma unroll
    for (int mi = 0; mi < 2; ++mi) {
        float psum[4] = {0.f,0.f,0.f,0.f};
        float psq[4]  = {0.f,0.f,0.f,0.f};
        #pragma unroll
        for (int ni = 0; ni < 4; ++ni) {
            int xx = xb + ni * 16 + l15;
            size_t base = (size_t)b * PB + (size_t)(1 + y0) * PROW
                          + ch * 4160 + (size_t)(1 + xx) * 32 + mi * 16 + q * 4;
            short4v o;
            #pragma unroll
            for (int g = 0; g < 4; ++g) {
                float v = acc[mi][ni][g];
                o[g] = f2bf(v);
                psum[g] += v;
                psq[g]  += v * v;
            }
            *(short4v*)&out[base] = o;
        }
        #pragma unroll
        for (int g = 0; g < 4; ++g) {
            float s = psum[g], s2 = psq[g];
            #pragma unroll
            for (int off = 1; off < 16; off <<= 1) {
                s  += __shfl_xor(s,  off, 64);
                s2 += __shfl_xor(s2, off, 64);
            }
            if (l15 == 0) {                       // 4 lanes (q=0..3), no contention
                int idx = pbase + mi * 16 + q * 4 + g;
                part_s[idx] = s;
                part_q[idx] = s2;
            }
        }
    }
}

// ---------------------------------------------------------------------------
// Reduce per-(row,pxhalf) partials -> (scale, bias) per (b,c). 1024 threads.
// ---------------------------------------------------------------------------
__global__ __launch_bounds__(256) void finalize_stats(const float* __restrict__ part_s,
                                                      const float* __restrict__ part_q,
                                                      float* __restrict__ nrm) {
    int i = blockIdx.x * 256 + threadIdx.x;
    if (i >= BATCH * CH) return;
    int b = i >> 6, c = i & 63;
    float s = 0.f, s2 = 0.f;
    const float* ps = part_s + (size_t)b * 128 * 2 * 64 + c;
    const float* pq = part_q + (size_t)b * 128 * 2 * 64 + c;
    #pragma unroll 4
    for (int r = 0; r < 256; ++r) {          // 128 rows x 2 pxhalves
        s  += ps[r * 64];
        s2 += pq[r * 64];
    }
    const float inv = 1.0f / (float)HW;
    float mean = s * inv;
    float var = s2 * inv - mean * mean;
    float scale = rsqrtf(var + 1e-5f);
    f32x2 sb = {scale, -mean * scale};
    ((f32x2*)nrm)[i] = sb;
}

// ---------------------------------------------------------------------------
// h = leaky(norm(y1)) IN PLACE on the padded buffer interior.
// ---------------------------------------------------------------------------
__global__ __launch_bounds__(256) void norm_leaky(short* __restrict__ hpad,
                                                  const float* __restrict__ nrm) {
    const int bid = blockIdx.x;
    const int b = bid >> 7, y = bid & 127;
    short* row = hpad + (size_t)b * PB + (size_t)(y + 1) * PROW;
    const int t = threadIdx.x;
    #pragma unroll
    for (int i = 0; i < 4; ++i) {
        int s = i * 256 + t;
        int c8 = s & 3, xx = (s >> 2) & 127, cc = s >> 9;
        short* p = row + cc * 4160 + (xx + 1) * 32 + c8 * 8;
        const f32x2* nb = (const f32x2*)nrm + b * CH + cc * 32 + c8 * 8;
        short8 v = *(const short8*)p;
        short8 o;
        #pragma unroll
        for (int j = 0; j < 8; ++j) {
            f32x2 sb = nb[j];
            float f = sb.x * bf2f(v[j]) + sb.y;
            f = f >= 0.f ? f : 0.2f * f;
            o[j] = f2bf(f);
        }
        *(short8*)p = o;
    }
}

// ---------------------------------------------------------------------------
// out = leaky(x + norm(y2)) : padded NHWC32 bf16 -> NCHW fp32, LDS transpose
// ---------------------------------------------------------------------------
__global__ __launch_bounds__(256) void final_kernel(const float* __restrict__ x,
                                                    const short* __restrict__ y2,
                                                    const float* __restrict__ nrm,
                                                    float* __restrict__ out) {
    __shared__ float tile[64 * 65];
    const int x0 = blockIdx.x * 64;
    const int y  = blockIdx.y;
    const int b  = blockIdx.z;
    const int t  = threadIdx.x;
    const f32x2* nb = (const f32x2*)nrm + b * CH;
    const size_t rowb = (size_t)b * PB + (size_t)(y + 1) * PROW;
    #pragma unroll
    for (int i = 0; i < 2; ++i) {
        int s = i * 256 + t;
        int xx = s >> 3;
        int c0 = (s & 7) * 8;
        int cc = c0 >> 5, cl = c0 & 31;
        short8 v = *(const short8*)&y2[rowb + cc * 4160 + (size_t)(x0 + xx + 1) * 32 + cl];
        #pragma unroll
        for (int j = 0; j < 8; ++j) {
            f32x2 sb = nb[c0 + j];
            tile[(c0 + j) * 65 + xx] = sb.x * bf2f(v[j]) + sb.y;
        }
    }
    __syncthreads();
    #pragma unroll
    for (int i = 0; i < 4; ++i) {
        int lin = i * 1024 + t * 4;
        int c = lin >> 6;
        int xx = lin & 63;
        size_t g = ((size_t)(b * CH + c) * IH + y) * IW + x0 + xx;
        f32x4 xv = *(const f32x4*)&x[g];
        f32x4 o;
        #pragma unroll
        for (int k = 0; k < 4; ++k) {
            float f = xv[k] + tile[c * 65 + xx + k];
            o[k] = f >= 0.f ? f : 0.2f * f;
        }
        *(f32x4*)&out[g] = o;
    }
}

// ---------------------------------------------------------------------------
extern "C" void kernel_launch(void* const* d_in, const int* in_sizes, int n_in,
                              void* d_out, int out_size, void* d_ws, size_t ws_size,
                              hipStream_t stream) {
    const float* x  = (const float*)d_in[0];
    const float* w1 = (const float*)d_in[1];
    const float* w2 = (const float*)d_in[2];
    float* out = (float*)d_out;
    char* ws = (char*)d_ws;

    const size_t SZ_PAD  = 34611200ull;        // one padded NHWC32 bf16 tensor
    const size_t SZ_PART = 1048576ull;         // 16*128*2*64 f32
    short* xpad = (short*)(ws);                // x (conv1 in), later y2 (conv2 out)
    short* hpad = (short*)(ws + SZ_PAD);       // y1 / h (conv1 out, conv2 in)
    short* w1t  = (short*)(ws + 2 * SZ_PAD);
    short* w2t  = (short*)(ws + 2 * SZ_PAD + 1179648ull);
    float* ps1  = (float*)(ws + 2 * SZ_PAD + 2359296ull);
    float* pq1  = (float*)(ws + 2 * SZ_PAD + 2359296ull + SZ_PART);
    float* ps2  = (float*)(ws + 2 * SZ_PAD + 2359296ull + 2 * SZ_PART);
    float* pq2  = (float*)(ws + 2 * SZ_PAD + 2359296ull + 3 * SZ_PART);
    float* nrm1 = (float*)(ws + 2 * SZ_PAD + 2359296ull + 4 * SZ_PART);
    float* nrm2 = nrm1 + BATCH * CH * 2;

    if (ws_size < 2 * SZ_PAD + 2359296ull + 4 * SZ_PART + 8192) return;

    pad_zero<<<32, 256, 0, stream>>>(xpad, hpad);
    prep_x<<<BATCH * IH, 256, 0, stream>>>(x, xpad);
    prep_w<<<512, 256, 0, stream>>>(w1, w2, w1t, w2t);
    conv_kernel<<<dim3(128, 16), 256, 0, stream>>>(xpad, w1t, hpad, ps1, pq1);
    finalize_stats<<<4, 256, 0, stream>>>(ps1, pq1, nrm1);
    norm_leaky<<<2048, 256, 0, stream>>>(hpad, nrm1);
    conv_kernel<<<dim3(128, 16), 256, 0, stream>>>(hpad, w2t, xpad, ps2, pq2);
    finalize_stats<<<4, 256, 0, stream>>>(ps2, pq2, nrm2);
    final_kernel<<<dim3(2, 128, 16), 256, 0, stream>>>(x, xpad, nrm2, out);
}